// Round 9
// baseline (254.187 us; speedup 1.0000x reference)
//
#include <hip/hip_runtime.h>
#include <math.h>

// dims
constexpr int Nn = 1024, Bb = 8, HIDc = 256, Hh = 8, DHc = 32;

typedef __bf16 bf16x8 __attribute__((ext_vector_type(8)));
typedef __bf16 bf16x4 __attribute__((ext_vector_type(4)));
typedef float  f32x4  __attribute__((ext_vector_type(4)));

// ---------------------------------------------------------------------------
// prep_k: fused one-time preprocessing.
//   [0,1088):     weight convert+transpose Wt[m][k] = bf16(W[k][m])
//   [1088,3136):  mask pack  mp[b][n][c*16 + quad*4 + t] byte, bit(2r+sel):
//                 sel0=(d==1), sel1=(d>=1), key = c*64 + t*16 + quad*4 + r
//   [3136,7232):  xinb[(b*1024+n)*256+k] = bf16(nodes[n][b][k] + PE(n,k))
// ---------------------------------------------------------------------------
struct WCvtArgs {
    const float* src[9];
    int K[9], M[9], dstOff[9], tiles[9];
};

__global__ __launch_bounds__(256)
void prep_k(WCvtArgs a, __bf16* __restrict__ Wt,
            const int* __restrict__ dist, unsigned char* __restrict__ mp,
            const float* __restrict__ nodes, __bf16* __restrict__ xinb)
{
    __shared__ float ts[32][33];
    const int tid = threadIdx.x;
    if (blockIdx.x < 1088) {
        int bid = blockIdx.x, i = 0;
        while (bid >= a.tiles[i]) { bid -= a.tiles[i]; ++i; }
        const int K = a.K[i], M = a.M[i];
        const int tilesM = M >> 5;
        const int m0 = (bid % tilesM) << 5, k0 = (bid / tilesM) << 5;
        const float* src = a.src[i];
        __bf16* dst = Wt + a.dstOff[i];
        const int tx = tid & 31, ty = tid >> 5;
        #pragma unroll
        for (int j = 0; j < 4; ++j)
            ts[ty + 8 * j][tx] = src[(size_t)(k0 + ty + 8 * j) * M + m0 + tx];
        __syncthreads();
        #pragma unroll
        for (int j = 0; j < 4; ++j)
            dst[(size_t)(m0 + ty + 8 * j) * K + k0 + tx] = (__bf16)ts[tx][ty + 8 * j];
    } else if (blockIdx.x < 3136) {
        const int idx = (blockIdx.x - 1088) * 256 + tid;   // 524288 items
        const int quad = idx & 3, c = (idx >> 2) & 15, q = (idx >> 6) & 1023, b = idx >> 16;
        const int* dp = dist + ((((size_t)b << 10) + q) << 10) + c * 64 + quad * 4;
        uchar4 out;
        unsigned char* po = &out.x;
        #pragma unroll
        for (int t = 0; t < 4; ++t) {
            const int4 v = *(const int4*)(dp + t * 16);
            unsigned int code = 0;
            const int dd[4] = {v.x, v.y, v.z, v.w};
            #pragma unroll
            for (int r = 0; r < 4; ++r)
                code |= ((dd[r] == 1 ? 1u : 0u) | (dd[r] >= 1 ? 2u : 0u)) << (2 * r);
            po[t] = (unsigned char)code;
        }
        *(uchar4*)(mp + ((((size_t)b << 10) + q) << 8) + (c << 4) + (quad << 2)) = out;
    } else {
        const int idx = (blockIdx.x - 3136) * 256 + tid;   // 1M items
        const int token = idx >> 7, k2 = (idx & 127) * 2;  // token = b*1024 + n
        const int b = token >> 10, n = token & 1023;
        const float e = (float)k2 * (1.0f / 256.0f);
        const float freq = exp2f(-13.287712379549449f * e);
        const float ang = (float)n * freq;
        const float2 nd = *(const float2*)(nodes + ((size_t)(n * 8 + b)) * 256 + k2);
        __bf16* p = xinb + (size_t)token * 256 + k2;
        p[0] = (__bf16)(nd.x + sinf(ang));
        p[1] = (__bf16)(nd.y + cosf(ang));
    }
}

// ---------------------------------------------------------------------------
// gemm4: one 256-col GEMM stage (16 A-rows), double-buffered LDS staging.
// Block = 4 waves = 4 col-quarters (64 cols each). 1 barrier per 64-k chunk;
// W prefetched 2 chunks ahead. Entry barrier protects aliased smem (trans).
// ---------------------------------------------------------------------------
template<int NCH>
__device__ __forceinline__ void gemm4(const bf16x8* af, const __bf16* __restrict__ wsrc,
                                      __bf16 (*wlds)[256][72], int mrow, int kcol,
                                      int cq, int col, int quad, f32x4* acc)
{
    constexpr int K = NCH * 64;
    bf16x8 wreg[8];
    #pragma unroll
    for (int i = 0; i < 8; ++i)
        wreg[i] = *(const bf16x8*)(wsrc + (size_t)(i * 32 + mrow) * K + kcol);
    __syncthreads();   // prior readers of aliased smem done
    #pragma unroll
    for (int i = 0; i < 8; ++i)
        *(bf16x8*)&wlds[0][i * 32 + mrow][kcol] = wreg[i];
    if (NCH > 1) {
        #pragma unroll
        for (int i = 0; i < 8; ++i)
            wreg[i] = *(const bf16x8*)(wsrc + (size_t)(i * 32 + mrow) * K + 64 + kcol);
    }
    __syncthreads();
    #pragma unroll
    for (int t = 0; t < 4; ++t) acc[t] = (f32x4){0.f, 0.f, 0.f, 0.f};
    for (int ck = 0; ck < NCH; ++ck) {
        #pragma unroll
        for (int t = 0; t < 4; ++t)
            #pragma unroll
            for (int kc = 0; kc < 2; ++kc) {
                const bf16x8 bfr = *(const bf16x8*)(&wlds[ck & 1][cq * 64 + t * 16 + col][kc * 32 + quad * 8]);
                acc[t] = __builtin_amdgcn_mfma_f32_16x16x32_bf16(af[ck * 2 + kc], bfr, acc[t], 0, 0, 0);
            }
        if (ck + 1 < NCH) {
            #pragma unroll
            for (int i = 0; i < 8; ++i)
                *(bf16x8*)&wlds[(ck + 1) & 1][i * 32 + mrow][kcol] = wreg[i];
            if (ck + 2 < NCH) {
                #pragma unroll
                for (int i = 0; i < 8; ++i)
                    wreg[i] = *(const bf16x8*)(wsrc + (size_t)(i * 32 + mrow) * K + (ck + 2) * 64 + kcol);
            }
        }
        __syncthreads();
    }
}

// ---------------------------------------------------------------------------
// layer_k: fused transformer block slab (16 token-rows per block, 512 blocks
// -> 2 blocks/CU for barrier overlap).
//   stage A: y = Ain @ w0 + b0 (+ xres if RESID) -> LN(g1,be1)
//   if FFN:  h1 = relu(xA @ w1 + b1);  y2 = h1 @ w2 + b2 + xA -> LN(g2,be2)
//   xout fp32: full (!XGATE), or only n==0 rows (XGATE)
//   if BNOUT: batch-norm across the 8 b-rows -> xout (d_out), no x write
//   if QKV:  q (scaled log2e/sqrt(DH); all rows if qfull, else n<128) /
//            k -> (B,H,N,DH); v -> V^T (B,H,DH,N)
// N0ROWS: grid=1; local row i -> global row (i&7)*1024 (n=0 rows of each b).
// Token layout (B,N,HID): token = b*1024 + n.
// ---------------------------------------------------------------------------
template<bool RESID, bool FFN, bool QKV, bool N0ROWS, bool XGATE, bool BNOUT>
__global__ __launch_bounds__(256)
void layer_k(const __bf16* __restrict__ Ain, const float* __restrict__ xres,
             const __bf16* __restrict__ w0, const float* __restrict__ b0,
             const float* __restrict__ g1, const float* __restrict__ be1,
             const __bf16* __restrict__ w1, const float* __restrict__ b1_,
             const __bf16* __restrict__ w2, const float* __restrict__ b2_,
             const float* __restrict__ g2, const float* __restrict__ be2,
             const __bf16* __restrict__ wq, const float* __restrict__ bq, int qfull,
             const float* __restrict__ bng, const float* __restrict__ bnb,
             float* __restrict__ xout,
             __bf16* __restrict__ qb, __bf16* __restrict__ kb, __bf16* __restrict__ vtb)
{
    __shared__ char smem[73728];                     // 2x wlds; trans aliases buf0
    __bf16 (*wlds)[256][72] = (__bf16 (*)[256][72])smem;
    __bf16 (*trans)[520] = (__bf16 (*)[520])smem;    // [16][520]
    __shared__ float red[4][16][2];

    const int tid = threadIdx.x;
    const int lane = tid & 63;
    const int cq = tid >> 6;                         // col-quarter 0..3
    const int col = lane & 15, quad = lane >> 4;
    const int row0 = blockIdx.x * 16;
    const int rowL = col;                            // local A-row for this lane
    const int mrow = tid >> 3, kcol = (tid & 7) * 8;

    const int rowAg = N0ROWS ? ((col & 7) << 10) : (row0 + col);

    // ---- stage A ----
    bf16x8 afA[8];
    #pragma unroll
    for (int kc = 0; kc < 8; ++kc)
        afA[kc] = *(const bf16x8*)(Ain + (size_t)rowAg * 256 + kc * 32 + quad * 8);
    f32x4 acc[4];
    gemm4<4>(afA, w0, wlds, mrow, kcol, cq, col, quad, acc);

    float val[4][4];
    {
        float bb[4], gm[4], bt[4];
        #pragma unroll
        for (int t = 0; t < 4; ++t) {
            const int cc = cq * 64 + t * 16 + col;
            bb[t] = b0[cc]; gm[t] = g1[cc]; bt[t] = be1[cc];
        }
        #pragma unroll
        for (int r = 0; r < 4; ++r) {
            const int rl = quad * 4 + r;
            const int rg = N0ROWS ? ((rl & 7) << 10) : (row0 + rl);
            float s1 = 0.f, s2 = 0.f;
            #pragma unroll
            for (int t = 0; t < 4; ++t) {
                float v = acc[t][r] + bb[t];
                if (RESID) v += xres[(size_t)rg * 256 + cq * 64 + t * 16 + col];
                val[r][t] = v; s1 += v; s2 += v * v;
            }
            s1 += __shfl_xor(s1, 1); s1 += __shfl_xor(s1, 2);
            s1 += __shfl_xor(s1, 4); s1 += __shfl_xor(s1, 8);
            s2 += __shfl_xor(s2, 1); s2 += __shfl_xor(s2, 2);
            s2 += __shfl_xor(s2, 4); s2 += __shfl_xor(s2, 8);
            if (col == 0) { red[cq][rl][0] = s1; red[cq][rl][1] = s2; }
        }
        __syncthreads();
        #pragma unroll
        for (int r = 0; r < 4; ++r) {
            const int rl = quad * 4 + r;
            const float s1 = red[0][rl][0] + red[1][rl][0] + red[2][rl][0] + red[3][rl][0];
            const float s2 = red[0][rl][1] + red[1][rl][1] + red[2][rl][1] + red[3][rl][1];
            const float mu = s1 * (1.0f / 256.0f);
            const float rv = rsqrtf(s2 * (1.0f / 256.0f) - mu * mu + 1e-5f);
            #pragma unroll
            for (int t = 0; t < 4; ++t) {
                const float o = (val[r][t] - mu) * rv * gm[t] + bt[t];
                val[r][t] = o;
                trans[rl][cq * 64 + t * 16 + col] = (__bf16)o;
                if (!FFN)   // fused1: this LN is the kernel's final LN
                    xout[(size_t)(row0 + rl) * 256 + cq * 64 + t * 16 + col] = o;
            }
        }
        __syncthreads();
    }

    if (FFN) {
        // ---- FFN: h1 = relu(xA @ W1 + b1), 2 m-halves of 256 ----
        bf16x8 af1[8];
        #pragma unroll
        for (int kc = 0; kc < 8; ++kc)
            af1[kc] = *(const bf16x8*)(&trans[rowL][kc * 32 + quad * 8]);
        bf16x4 h1p[2][4];
        #pragma unroll
        for (int mh = 0; mh < 2; ++mh) {
            f32x4 accb[4];
            gemm4<4>(af1, w1 + (size_t)mh * 256 * 256, wlds, mrow, kcol, cq, col, quad, accb);
            #pragma unroll
            for (int t = 0; t < 4; ++t) {
                const float bbv = b1_[mh * 256 + cq * 64 + t * 16 + col];
                #pragma unroll
                for (int r = 0; r < 4; ++r)
                    h1p[mh][t][r] = (__bf16)fmaxf(accb[t][r] + bbv, 0.f);
            }
        }
        __syncthreads();
        #pragma unroll
        for (int mh = 0; mh < 2; ++mh)
            #pragma unroll
            for (int t = 0; t < 4; ++t)
                #pragma unroll
                for (int r = 0; r < 4; ++r)
                    trans[quad * 4 + r][mh * 256 + cq * 64 + t * 16 + col] = h1p[mh][t][r];
        __syncthreads();

        // ---- y2 = h1 @ W2 + b2 + xA -> LN2 ----
        bf16x8 af2[16];
        #pragma unroll
        for (int kc = 0; kc < 16; ++kc)
            af2[kc] = *(const bf16x8*)(&trans[rowL][kc * 32 + quad * 8]);
        f32x4 accc[4];
        gemm4<8>(af2, w2, wlds, mrow, kcol, cq, col, quad, accc);

        float bb[4], gm[4], bt[4];
        #pragma unroll
        for (int t = 0; t < 4; ++t) {
            const int cc = cq * 64 + t * 16 + col;
            bb[t] = b2_[cc]; gm[t] = g2[cc]; bt[t] = be2[cc];
        }
        #pragma unroll
        for (int r = 0; r < 4; ++r) {
            const int rl = quad * 4 + r;
            float s1 = 0.f, s2 = 0.f;
            #pragma unroll
            for (int t = 0; t < 4; ++t) {
                const float v = accc[t][r] + bb[t] + val[r][t];
                val[r][t] = v; s1 += v; s2 += v * v;
            }
            s1 += __shfl_xor(s1, 1); s1 += __shfl_xor(s1, 2);
            s1 += __shfl_xor(s1, 4); s1 += __shfl_xor(s1, 8);
            s2 += __shfl_xor(s2, 1); s2 += __shfl_xor(s2, 2);
            s2 += __shfl_xor(s2, 4); s2 += __shfl_xor(s2, 8);
            if (col == 0) { red[cq][rl][0] = s1; red[cq][rl][1] = s2; }
        }
        __syncthreads();
        #pragma unroll
        for (int r = 0; r < 4; ++r) {
            const int rl = quad * 4 + r;
            const float s1 = red[0][rl][0] + red[1][rl][0] + red[2][rl][0] + red[3][rl][0];
            const float s2 = red[0][rl][1] + red[1][rl][1] + red[2][rl][1] + red[3][rl][1];
            const float mu = s1 * (1.0f / 256.0f);
            const float rv = rsqrtf(s2 * (1.0f / 256.0f) - mu * mu + 1e-5f);
            const int rg = N0ROWS ? ((rl & 7) << 10) : (row0 + rl);
            #pragma unroll
            for (int t = 0; t < 4; ++t) {
                const float o = (val[r][t] - mu) * rv * gm[t] + bt[t];
                val[r][t] = o;
                if (QKV) trans[rl][cq * 64 + t * 16 + col] = (__bf16)o;
                if (!BNOUT) {
                    const bool wr = XGATE ? ((rg & 1023) == 0) : true;
                    if (wr) xout[(size_t)rg * 256 + cq * 64 + t * 16 + col] = o;
                }
            }
        }
        if (BNOUT) {
            // batch-norm across b (rows 0..7; quads 2,3 are duplicates)
            #pragma unroll
            for (int t = 0; t < 4; ++t) {
                const int cc = cq * 64 + t * 16 + col;
                float s1 = val[0][t] + val[1][t] + val[2][t] + val[3][t];
                float s2 = val[0][t] * val[0][t] + val[1][t] * val[1][t]
                         + val[2][t] * val[2][t] + val[3][t] * val[3][t];
                s1 += __shfl_xor(s1, 16);
                s2 += __shfl_xor(s2, 16);
                const float mu = s1 * 0.125f;
                const float rv = rsqrtf(s2 * 0.125f - mu * mu + 1e-5f);
                const float gg = bng[cc], bb2 = bnb[cc];
                if (quad < 2) {
                    #pragma unroll
                    for (int r = 0; r < 4; ++r)
                        xout[(size_t)(quad * 4 + r) * 256 + cc] = (val[r][t] - mu) * rv * gg + bb2;
                }
            }
        }
        __syncthreads();
    }

    if (QKV) {
        bf16x8 af3[8];
        #pragma unroll
        for (int kc = 0; kc < 8; ++kc)
            af3[kc] = *(const bf16x8*)(&trans[rowL][kc * 32 + quad * 8]);
        const int bq_ = row0 >> 10;                  // batch (uniform per block)
        const int n0q = (row0 & 1023) + quad * 4;    // n of this lane's C-rows
        const bool qneed = qfull || ((row0 & 1023) < 128);
        for (int cg = 0; cg < 3; ++cg) {
            if (cg == 0 && !qneed) continue;         // block-uniform skip
            f32x4 accq[4];
            gemm4<4>(af3, wq + (size_t)cg * 256 * 256, wlds, mrow, kcol, cq, col, quad, accq);
            if (cg == 2) {
                #pragma unroll
                for (int t = 0; t < 4; ++t) {
                    const int cc = cq * 64 + t * 16 + col;
                    const int h = cc >> 5, dh = cc & 31;
                    const float bbv = bq[512 + cc];
                    bf16x4 p;
                    #pragma unroll
                    for (int r = 0; r < 4; ++r) p[r] = (__bf16)(accq[t][r] + bbv);
                    *(bf16x4*)(vtb + ((((size_t)(bq_ * 8 + h)) * 32 + dh) << 10) + n0q) = p;
                }
            } else {
                const float qs = (cg == 0) ? 0.25505402616305625f : 1.0f;  // log2e/sqrt(32)
                __bf16* dst = (cg == 0) ? qb : kb;
                #pragma unroll
                for (int t = 0; t < 4; ++t) {
                    const int cc = cq * 64 + t * 16 + col;
                    const int h = cc >> 5, dh = cc & 31;
                    const float bbv = bq[cg * 256 + cc];
                    #pragma unroll
                    for (int r = 0; r < 4; ++r)
                        dst[((((size_t)(bq_ * 8 + h)) << 10) + n0q + r) * 32 + dh] =
                            (__bf16)((accq[t][r] + bbv) * qs);
                }
            }
        }
    }
}

// ---------------------------------------------------------------------------
// MFMA flash attention. Grid (64 bh-swizzled, NQC q-chunks); block 4 waves x 32 q.
// XCD j owns batch b=j (L2-resident K/V/Q/mask). K prefetch + double-buffered P.
// ---------------------------------------------------------------------------
__global__ __launch_bounds__(256)
void attn_mfma(const __bf16* __restrict__ Qb, const __bf16* __restrict__ Kb,
               const __bf16* __restrict__ Vt, const unsigned char* __restrict__ MP,
               __bf16* __restrict__ O)
{
    __shared__ __bf16 pbuf[2][4][2][16][72];
    const int tid = threadIdx.x;
    const int lane = tid & 63;
    const int wv = tid >> 6;
    const int col = lane & 15;
    const int quad = lane >> 4;
    const int xr = blockIdx.x;
    const int bh = ((xr & 7) << 3) | (xr >> 3);     // XCD = x%8 = batch b
    const int b = bh >> 3, h = bh & 7;
    const int qbase = blockIdx.y * 128 + wv * 32;
    const int hsel = (h < 2) ? 0 : 1;
    const bool masked = (h < 6);

    bf16x8 qf[2];
    #pragma unroll
    for (int j = 0; j < 2; ++j)
        qf[j] = *(const bf16x8*)(Qb + ((size_t)bh * Nn + qbase + j * 16 + col) * DHc + quad * 8);

    bf16x8 onesf;
    {
        const __bf16 one = (__bf16)1.0f, zero = (__bf16)0.0f;
        #pragma unroll
        for (int j = 0; j < 8; ++j) onesf[j] = (col == 0) ? one : zero;
    }

    f32x4 O0[2], O1[2], OL[2];
    #pragma unroll
    for (int j = 0; j < 2; ++j) {
        O0[j] = (f32x4){0.f, 0.f, 0.f, 0.f};
        O1[j] = (f32x4){0.f, 0.f, 0.f, 0.f};
        OL[j] = (f32x4){0.f, 0.f, 0.f, 0.f};
    }
    const f32x4 zf = {0.f, 0.f, 0.f, 0.f};
    const __bf16* kbase = Kb + (size_t)bh * Nn * DHc;

    bf16x8 kf[4];
    #pragma unroll
    for (int t = 0; t < 4; ++t)
        kf[t] = *(const bf16x8*)(kbase + (size_t)(t * 16 + col) * DHc + quad * 8);

    for (int c = 0; c < 16; ++c) {
        bf16x8 kn[4];
        if (c < 15)
            #pragma unroll
            for (int t = 0; t < 4; ++t)
                kn[t] = *(const bf16x8*)(kbase + (size_t)((c + 1) * 64 + t * 16 + col) * DHc + quad * 8);
        uchar4 mk[2];
        if (masked)
            #pragma unroll
            for (int j = 0; j < 2; ++j)
                mk[j] = *(const uchar4*)(MP + ((((size_t)b << 10) + qbase + j * 16 + col) << 8)
                                            + (c << 4) + (quad << 2));
        #pragma unroll
        for (int j = 0; j < 2; ++j) {
            f32x4 S[4];
            #pragma unroll
            for (int t = 0; t < 4; ++t)
                S[t] = __builtin_amdgcn_mfma_f32_16x16x32_bf16(kf[t], qf[j], zf, 0, 0, 0);
            if (masked) {
                const unsigned char mb[4] = {mk[j].x, mk[j].y, mk[j].z, mk[j].w};
                #pragma unroll
                for (int t = 0; t < 4; ++t)
                    #pragma unroll
                    for (int r = 0; r < 4; ++r)
                        if (!((mb[t] >> (2 * r + hsel)) & 1)) S[t][r] = -INFINITY;
            }
            #pragma unroll
            for (int t = 0; t < 4; ++t) {
                bf16x4 p4;
                #pragma unroll
                for (int r = 0; r < 4; ++r)
                    p4[r] = (__bf16)__builtin_amdgcn_exp2f(S[t][r]);
                *(bf16x4*)(&pbuf[c & 1][wv][j][col][t * 16 + quad * 4]) = p4;
            }
        }
        const __bf16* vp = Vt + (size_t)bh * DHc * Nn + c * 64 + quad * 8;
        #pragma unroll
        for (int kh = 0; kh < 2; ++kh) {
            const bf16x8 v0 = *(const bf16x8*)(vp + (size_t)col * Nn + kh * 32);
            const bf16x8 v1 = *(const bf16x8*)(vp + (size_t)(col + 16) * Nn + kh * 32);
            #pragma unroll
            for (int j = 0; j < 2; ++j) {
                const bf16x8 pf = *(const bf16x8*)(&pbuf[c & 1][wv][j][col][kh * 32 + quad * 8]);
                O0[j] = __builtin_amdgcn_mfma_f32_16x16x32_bf16(pf, v0, O0[j], 0, 0, 0);
                O1[j] = __builtin_amdgcn_mfma_f32_16x16x32_bf16(pf, v1, O1[j], 0, 0, 0);
                OL[j] = __builtin_amdgcn_mfma_f32_16x16x32_bf16(pf, onesf, OL[j], 0, 0, 0);
            }
        }
        if (c < 15)
            #pragma unroll
            for (int t = 0; t < 4; ++t) kf[t] = kn[t];
    }
    #pragma unroll
    for (int j = 0; j < 2; ++j)
        #pragma unroll
        for (int r = 0; r < 4; ++r) {
            const float Lr = __shfl(OL[j][r], lane & 48);
            const float inv = 1.0f / Lr;
            const int q = qbase + j * 16 + quad * 4 + r;
            __bf16* op = O + ((size_t)(b * 1024 + q)) * 256 + h * 32 + col;
            op[0]  = (__bf16)(O0[j][r] * inv);
            op[16] = (__bf16)(O1[j][r] * inv);
        }
}

extern "C" void kernel_launch(void* const* d_in, const int* in_sizes, int n_in,
                              void* d_out, int out_size, void* d_ws, size_t ws_size,
                              hipStream_t stream)
{
    const float* nodes   = (const float*)d_in[0];
    const int*   dist    = (const int*)  d_in[1];
    const float* W_in    = (const float*)d_in[2];
    const float* b_in    = (const float*)d_in[3];
    const float* ln_in_g = (const float*)d_in[4];
    const float* ln_in_b = (const float*)d_in[5];
    const float* Wqkv    = (const float*)d_in[6];
    const float* bqkv    = (const float*)d_in[7];
    const float* Wo      = (const float*)d_in[8];
    const float* bo      = (const float*)d_in[9];
    const float* ln1_g   = (const float*)d_in[10];
    const float* ln1_b   = (const float*)d_in[11];
    const float* W1      = (const float*)d_in[12];
    const float* b1      = (const float*)d_in[13];
    const float* W2      = (const float*)d_in[14];
    const float* b2      = (const float*)d_in[15];
    const float* ln2_g   = (const float*)d_in[16];
    const float* ln2_b   = (const float*)d_in[17];
    const float* bn_g    = (const float*)d_in[18];
    const float* bn_b    = (const float*)d_in[19];

    // workspace (byte offsets), 28.25 MB used
    char* ws = (char*)d_ws;
    float*  x   = (float*)(ws);                          // 8 MB fp32 residual (B,N,HID)
    unsigned char* mp = (unsigned char*)(ws + 8388608);  // 2 MB packed mask
    __bf16* wt  = (__bf16*)(ws + 10485760);              // 2.25 MB weights^T
    __bf16* qb  = (__bf16*)(ws + 12845056);              // 4 MB
    __bf16* kb  = (__bf16*)(ws + 17039360);              // 4 MB
    __bf16* vtb = (__bf16*)(ws + 21233664);              // 4 MB (V^T)
    __bf16* ob  = (__bf16*)(ws + 25427968);              // 4 MB attn out
    __bf16* xinb = ob;   // aliases ob (ob first written after fused1 consumed xinb)

    WCvtArgs wa;
    wa.src[0] = W_in;           wa.K[0] = 256; wa.M[0] = 256; wa.dstOff[0] = 0;
    wa.src[1] = Wqkv;           wa.K[1] = 256; wa.M[1] = 768; wa.dstOff[1] = 65536;
    wa.src[2] = Wqkv + 196608;  wa.K[2] = 256; wa.M[2] = 768; wa.dstOff[2] = 262144;
    wa.src[3] = Wo;             wa.K[3] = 256; wa.M[3] = 256; wa.dstOff[3] = 458752;
    wa.src[4] = Wo + 65536;     wa.K[4] = 256; wa.M[4] = 256; wa.dstOff[4] = 524288;
    wa.src[5] = W1;             wa.K[5] = 256; wa.M[5] = 512; wa.dstOff[5] = 589824;
    wa.src[6] = W1 + 131072;    wa.K[6] = 256; wa.M[6] = 512; wa.dstOff[6] = 720896;
    wa.src[7] = W2;             wa.K[7] = 512; wa.M[7] = 256; wa.dstOff[7] = 851968;
    wa.src[8] = W2 + 131072;    wa.K[8] = 512; wa.M[8] = 256; wa.dstOff[8] = 983040;
    for (int i = 0; i < 9; ++i) wa.tiles[i] = (wa.K[i] >> 5) * (wa.M[i] >> 5);

    prep_k<<<7232, 256, 0, stream>>>(wa, wt, dist, mp, nodes, xinb);

    // fused1: x = LN(xin @ W_in + b_in); QKV layer 0 (full q)
    layer_k<false, false, true, false, false, false><<<512, 256, 0, stream>>>(
        xinb, nullptr, wt, b_in, ln_in_g, ln_in_b,
        nullptr, nullptr, nullptr, nullptr, nullptr, nullptr,
        wt + 65536, bqkv, 1, nullptr, nullptr, x, qb, kb, vtb);

    attn_mfma<<<dim3(64, 8), 256, 0, stream>>>(qb, kb, vtb, mp, ob);

    // fused2: Wo0+LN1+FFN0+LN2 (x stored only n==0); QKV layer 1 (q only n<128)
    layer_k<true, true, true, false, true, false><<<512, 256, 0, stream>>>(
        ob, x, wt + 458752, bo, ln1_g, ln1_b,
        wt + 589824, b1, wt + 851968, b2, ln2_g, ln2_b,
        wt + 262144, bqkv + 768, 0, nullptr, nullptr, x, qb, kb, vtb);

    // attn layer 1: only q in [0,128) needed (output consumed only at n==0)
    attn_mfma<<<dim3(64, 1), 256, 0, stream>>>(qb, kb, vtb, mp, ob);

    // fused3: Wo1+LN1+FFN1+LN2 + batch-norm on the 8 n==0 rows (1 block)
    layer_k<true, true, false, true, true, true><<<1, 256, 0, stream>>>(
        ob, x, wt + 524288, bo + 256, ln1_g + 256, ln1_b + 256,
        wt + 720896, b1 + 512, wt + 983040, b2 + 256, ln2_g + 256, ln2_b + 256,
        nullptr, nullptr, 0, bn_g, bn_b, (float*)d_out, nullptr, nullptr, nullptr);
}